// Round 6
// baseline (172.190 us; speedup 1.0000x reference)
//
#include <hip/hip_runtime.h>
#include <hip/hip_bf16.h>
#include <stdint.h>

typedef __bf16 bf16;
typedef __bf16 bf16x8 __attribute__((ext_vector_type(8)));
typedef __bf16 bf16x4 __attribute__((ext_vector_type(4)));
typedef __bf16 bf16x2 __attribute__((ext_vector_type(2)));
typedef float f32x4 __attribute__((ext_vector_type(4)));
typedef float f32x2 __attribute__((ext_vector_type(2)));
typedef int i32x4 __attribute__((ext_vector_type(4)));

#define GAS __attribute__((address_space(1)))
#define LAS __attribute__((address_space(3)))

#define NROIS 1000
#define DEPTH 256
#define CIN 320
#define KDIM 15680      // 320*49 = 245 K-tiles of 64 exactly
#define KPAD 16128      // 252 tiles = 14 z-slices x 18
#define TABS 120

// NHWC offsets (floats, within T region)
#define T_P2 0
#define T_P3 6553600
#define T_P4 8192000
#define T_P5 8601600
#define T_RNG 8704000

// ws layout (aliased; stream-ordered). Budget >= 100.4 MB.
#define OFF_A    0ULL
#define OFF_PART 33030144ULL
#define OFF_TAB  33030144ULL
#define OFF_T    33554432ULL
#define OFF_X1B  0ULL
#define OFF_X2   2621440ULL

// ---------------- prep: CHW->HWC transpose + per-ROI tables (merged) ----------------
__global__ __launch_bounds__(256) void k_prep(const float* __restrict__ p2, const float* __restrict__ p3,
                                              const float* __restrict__ p4, const float* __restrict__ p5,
                                              const float* __restrict__ rng, float* __restrict__ T,
                                              const float* __restrict__ rois, float* __restrict__ tab) {
    __shared__ float tile[64][65];
    int bid = blockIdx.x, t = threadIdx.x;
    if (bid >= 2528) {   // roi table blocks
        int n = (bid - 2528) * 256 + t;
        if (n >= NROIS) return;
        float y1 = rois[n*4+0], x1 = rois[n*4+1], y2 = rois[n*4+2], x2 = rois[n*4+3];
        float h = __fsub_rn(y2, y1), w = __fsub_rn(x2, x1);
        float rl = 4.0f + logf(sqrtf(h * w) / (224.0f / 640.0f)) / logf(2.0f);
        int lvl = (int)rintf(rl);
        lvl = min(5, max(2, lvl));
        float* tt = tab + (size_t)n * TABS;
        tt[112] = (float)lvl;
        int Hs0 = 160 >> (lvl - 2);
        for (int g = 0; g < 2; g++) {
            int H = g ? 160 : Hs0;
            float* tg = tt + g * 56;
            float fH = (float)(H - 1);
            float a = __fmul_rn(y1, fH);
            float s = __fdiv_rn(__fmul_rn(h, fH), 6.0f);
            for (int i = 0; i < 7; i++) {
                float iny = __fadd_rn(a, __fmul_rn((float)i, s));
                float tp = floorf(iny), bt = ceilf(iny);
                tg[i]      = (float)min(H-1, max(0, (int)tp));
                tg[7 + i]  = (float)min(H-1, max(0, (int)bt));
                tg[14 + i] = iny - tp;
                tg[21 + i] = (iny >= 0.0f && iny <= fH) ? 1.0f : 0.0f;
            }
            a = __fmul_rn(x1, fH);
            s = __fdiv_rn(__fmul_rn(w, fH), 6.0f);
            for (int j = 0; j < 7; j++) {
                float inx = __fadd_rn(a, __fmul_rn((float)j, s));
                float lf = floorf(inx), rt = ceilf(inx);
                tg[28 + j] = (float)min(H-1, max(0, (int)lf));
                tg[35 + j] = (float)min(H-1, max(0, (int)rt));
                tg[42 + j] = inx - lf;
                tg[49 + j] = (inx >= 0.0f && inx <= fH) ? 1.0f : 0.0f;
            }
        }
        return;
    }
    const float* src; float* dst; int C, X, loc;
    if (bid < 1600)      { src = p2;  dst = T + T_P2;  C = 256; X = 25600; loc = bid; }
    else if (bid < 2000) { src = p3;  dst = T + T_P3;  C = 256; X = 6400;  loc = bid - 1600; }
    else if (bid < 2100) { src = p4;  dst = T + T_P4;  C = 256; X = 1600;  loc = bid - 2000; }
    else if (bid < 2128) { src = p5;  dst = T + T_P5;  C = 256; X = 400;   loc = bid - 2100; }
    else                 { src = rng; dst = T + T_RNG; C = 64;  X = 25600; loc = bid - 2128; }
    int xtiles = (X + 63) >> 6;
    int xt = loc % xtiles, ct = loc / xtiles;
    int x0 = xt << 6, c0 = ct << 6;
    #pragma unroll
    for (int r = 0; r < 16; r++) {
        int lin = r * 256 + t;
        int lc = lin >> 6, lx = lin & 63;
        int x = x0 + lx;
        tile[lc][lx] = (x < X) ? src[(size_t)(c0 + lc) * X + x] : 0.0f;
    }
    __syncthreads();
    #pragma unroll
    for (int r = 0; r < 16; r++) {
        int lin = r * 256 + t;
        int lxx = lin >> 6, lcc = lin & 63;
        int x = x0 + lxx;
        if (x < X) dst[(size_t)x * C + c0 + lcc] = tile[lcc][lxx];
    }
}

// ---------------- crop_and_resize from NHWC ----------------
#define RES_S 329
__global__ __launch_bounds__(256) void k_crop2(const float* __restrict__ T, const float* __restrict__ tab,
                                               float* __restrict__ out_rf, bf16* __restrict__ A) {
    int n = blockIdx.x, t = threadIdx.x;
    if (n >= NROIS) {                 // zero-pad A rows 1000..1023
        i32x4* row = (i32x4*)(A + (size_t)n * KPAD);
        for (int i = t; i < KPAD * 2 / 16; i += 256) row[i] = i32x4{0,0,0,0};
        return;
    }
    __shared__ float res[49 * RES_S];
    __shared__ float tl_[TABS];
    if (t < TABS) tl_[t] = tab[(size_t)n * TABS + t];
    __syncthreads();
    int lvl = (int)tl_[112];
    int H = 160 >> (lvl - 2);
    int toff = (lvl == 2) ? T_P2 : (lvl == 3) ? T_P3 : (lvl == 4) ? T_P4 : T_P5;
    const float* F = T + toff;
    {
        int q = t & 63, pl = t >> 6, c4 = q * 4;
        for (int g = 0; g < 13; g++) {
            int pos = g * 4 + pl;
            if (pos < 49) {
                int i = pos / 7, j = pos % 7;
                int ti = (int)tl_[i],      bi = (int)tl_[7 + i];
                int li = (int)tl_[28 + j], ri = (int)tl_[35 + j];
                float ly = tl_[14 + i], lx = tl_[42 + j];
                float valid = tl_[21 + i] * tl_[49 + j];
                f32x4 vtl = *(const f32x4*)(F + (size_t)(ti * H + li) * 256 + c4);
                f32x4 vtr = *(const f32x4*)(F + (size_t)(ti * H + ri) * 256 + c4);
                f32x4 vbl = *(const f32x4*)(F + (size_t)(bi * H + li) * 256 + c4);
                f32x4 vbr = *(const f32x4*)(F + (size_t)(bi * H + ri) * 256 + c4);
                f32x4 top = vtl + (vtr - vtl) * lx;
                f32x4 bot = vbl + (vbr - vbl) * lx;
                f32x4 v = top + (bot - top) * ly;
                if (valid == 0.0f) v = f32x4{0.f,0.f,0.f,0.f};
                *(f32x4*)(&res[pos * RES_S + c4]) = v;
            }
        }
    }
    {
        int q = t & 15, pl = t >> 4, c4 = q * 4;
        const float* R = T + T_RNG;
        for (int g = 0; g < 4; g++) {
            int pos = g * 16 + pl;
            if (pos < 49) {
                int i = pos / 7, j = pos % 7;
                int ti = (int)tl_[56 + i], bi = (int)tl_[63 + i];
                int li = (int)tl_[84 + j], ri = (int)tl_[91 + j];
                float ly = tl_[70 + i], lx = tl_[98 + j];
                float valid = tl_[77 + i] * tl_[105 + j];
                f32x4 vtl = *(const f32x4*)(R + (size_t)(ti * 160 + li) * 64 + c4);
                f32x4 vtr = *(const f32x4*)(R + (size_t)(ti * 160 + ri) * 64 + c4);
                f32x4 vbl = *(const f32x4*)(R + (size_t)(bi * 160 + li) * 64 + c4);
                f32x4 vbr = *(const f32x4*)(R + (size_t)(bi * 160 + ri) * 64 + c4);
                f32x4 top = vtl + (vtr - vtl) * lx;
                f32x4 bot = vbl + (vbr - vbl) * lx;
                f32x4 v = top + (bot - top) * ly;
                if (valid == 0.0f) v = f32x4{0.f,0.f,0.f,0.f};
                *(f32x4*)(&res[pos * RES_S + 256 + c4]) = v;
            }
        }
    }
    __syncthreads();
    size_t ob = (size_t)n * KDIM;
    size_t ab = (size_t)n * KPAD;
    for (int k = 0; k < 31; k++) {
        int i2 = (k * 256 + t) * 2;
        if (i2 < KDIM) {
            float e0 = res[(i2 % 49) * RES_S + i2 / 49];
            int i3 = i2 + 1;
            float e1 = res[(i3 % 49) * RES_S + i3 / 49];
            *(f32x2*)(out_rf + ob + i2) = f32x2{e0, e1};
            bf16x2 b2; b2[0] = (bf16)e0; b2[1] = (bf16)e1;
            *(bf16x2*)(A + ab + i2) = b2;
        }
    }
    if (t < 56) ((i32x4*)(A + ab + KDIM))[t] = i32x4{0,0,0,0};
}

// ---------------- 256x256 8-phase GEMM: [256][64] XOR-swizzled LDS (R4-proven,
// zero conflicts) + counted vmcnt + 2-barrier phases (m201 discipline).
// A bf16 [M x KA] via global_load_lds, pre-swizzled source cols.
// B f32 [N x KB] reg-loaded 3 phases early -> cvt -> swizzled ds_write.
// C = A * B^T -> part[z]. NT even.
template<int REMAP>
__global__ __launch_bounds__(512, 2)
void k_gemm8p(const bf16* __restrict__ A, const float* __restrict__ Bf,
              float* __restrict__ part, const int KA, const int KB, const int NT) {
    __shared__ bf16 sA[2][16384];   // [buf][256 rows][64 cols], slot^(row&7)
    __shared__ bf16 sB[2][16384];
    int tid = threadIdx.x;
    int l = tid & 63, w = tid >> 6;
    int bx, by, bz;
    if (REMAP) {
        int id = blockIdx.x;
        int z, j;
        if (id < 128) { z = id & 7; j = id >> 3; }
        else { int r = id - 128; z = 8 + (r >> 4); j = r & 15; }
        bx = j & 3; by = j >> 2; bz = z;
    } else { bx = blockIdx.x; by = blockIdx.y; bz = blockIdx.z; }
    int tm = bx * 256, tn = by * 256;
    int t0 = bz * NT;
    const int maxTA = KA / 64 - 1;
    const int maxBC = KB - 64;

    int wr128 = (w >> 2) * 128;
    int wc64  = (w & 3) * 64;
    int lr = l & 15, lh = l >> 4;
    int sxor = lr & 7;

    int idx0 = tid;
    int arl = idx0 >> 3, aslot = idx0 & 7;
    const bf16* Asrc = A + (size_t)(tm + arl) * KA + ((aslot ^ (arl & 7)) << 3);
    int brw = idx0 >> 2, bc4 = idx0 & 3;
    const float* Bsrc = Bf + (size_t)(tn + brw) * KB + bc4 * 16;
    int bsw0 = ((bc4 * 2) ^ (brw & 7)) << 3;
    int bsw1 = ((bc4 * 2 + 1) ^ (brw & 7)) << 3;
    int brow64 = brw * 64;

    f32x4 acc[8][4] = {};
    bf16x8 af[8], b0, b1;
    f32x4 lb0_0, lb0_1, lb0_2, lb0_3;
    f32x4 lb1_0, lb1_1, lb1_2, lb1_3;

#define GLLA_H(bufc, h_, t_) do { int tt_ = min((t_), maxTA); size_t kc_ = (size_t)tt_ * 64; \
    __builtin_amdgcn_global_load_lds((const GAS void*)(Asrc + (size_t)((h_) * 128) * KA + kc_), \
        (LAS void*)(&sA[bufc][(h_) * 8192 + idx0 * 8]), 16, 0, 0); \
    __builtin_amdgcn_global_load_lds((const GAS void*)(Asrc + (size_t)((h_) * 128 + 64) * KA + kc_), \
        (LAS void*)(&sA[bufc][(h_) * 8192 + 4096 + idx0 * 8]), 16, 0, 0); \
} while (0)

#define LB_H(R0, R1, R2, R3, h_, t_) do { \
    const float* p_ = Bsrc + (size_t)((h_) * 128) * KB + min((t_) * 64, maxBC); \
    R0 = *(const f32x4*)(p_);     R1 = *(const f32x4*)(p_ + 4); \
    R2 = *(const f32x4*)(p_ + 8); R3 = *(const f32x4*)(p_ + 12); \
} while (0)

#define WB_H(bufc, h_, R0, R1, R2, R3) do { bf16x8 w0_, w1_; \
    _Pragma("unroll") for (int e_ = 0; e_ < 4; e_++) { \
        w0_[e_] = (bf16)R0[e_]; w0_[4 + e_] = (bf16)R1[e_]; \
        w1_[e_] = (bf16)R2[e_]; w1_[4 + e_] = (bf16)R3[e_]; } \
    *(bf16x8*)(&sB[bufc][(h_) * 8192 + brow64 + bsw0]) = w0_; \
    *(bf16x8*)(&sB[bufc][(h_) * 8192 + brow64 + bsw1]) = w1_; \
} while (0)

#define RD_AF(bufc, ks_) do { _Pragma("unroll") for (int mf_ = 0; mf_ < 8; mf_++) \
    af[mf_] = *(const bf16x8*)(&sA[bufc][(wr128 + mf_ * 16 + lr) * 64 + ((((ks_) * 4 + lh) ^ sxor) << 3)]); \
} while (0)

#define RD_BF(bufc, ks_, nh_) do { \
    b0 = *(const bf16x8*)(&sB[bufc][(wc64 + (nh_) * 32 + lr) * 64 + ((((ks_) * 4 + lh) ^ sxor) << 3)]); \
    b1 = *(const bf16x8*)(&sB[bufc][(wc64 + (nh_) * 32 + 16 + lr) * 64 + ((((ks_) * 4 + lh) ^ sxor) << 3)]); \
} while (0)

#define MM(nh_) do { \
    __builtin_amdgcn_sched_barrier(0); \
    __builtin_amdgcn_s_barrier(); \
    asm volatile("s_waitcnt lgkmcnt(0)" ::: "memory"); \
    __builtin_amdgcn_sched_barrier(0); \
    __builtin_amdgcn_s_setprio(1); \
    _Pragma("unroll") for (int mf_ = 0; mf_ < 8; mf_++) { \
        acc[mf_][(nh_) * 2]     = __builtin_amdgcn_mfma_f32_16x16x32_bf16(af[mf_], b0, acc[mf_][(nh_) * 2], 0, 0, 0); \
        acc[mf_][(nh_) * 2 + 1] = __builtin_amdgcn_mfma_f32_16x16x32_bf16(af[mf_], b1, acc[mf_][(nh_) * 2 + 1], 0, 0, 0); } \
    __builtin_amdgcn_s_setprio(0); \
    __builtin_amdgcn_s_barrier(); \
} while (0)

    // ---- prologue: tile t0 fully staged into buf0; B(t0+1) loads in regs ----
    GLLA_H(0, 0, t0); GLLA_H(0, 1, t0);
    LB_H(lb0_0, lb0_1, lb0_2, lb0_3, 0, t0);
    LB_H(lb1_0, lb1_1, lb1_2, lb1_3, 1, t0);
    WB_H(0, 0, lb0_0, lb0_1, lb0_2, lb0_3);   // compiler vmcnt drains A(t0)+B(t0)
    WB_H(0, 1, lb1_0, lb1_1, lb1_2, lb1_3);
    LB_H(lb0_0, lb0_1, lb0_2, lb0_3, 0, t0 + 1);
    LB_H(lb1_0, lb1_1, lb1_2, lb1_3, 1, t0 + 1);
    asm volatile("s_waitcnt lgkmcnt(0)" ::: "memory");
    __builtin_amdgcn_s_barrier();

    const int NI = NT >> 1;
    for (int i = 0; i < NI; i++) {
        int u = t0 + 2 * i;
        // ph1: compute(buf0,ks0,nh0) | stage A(u+1).h0, write B(u+1).h0
        RD_AF(0, 0); RD_BF(0, 0, 0);
        GLLA_H(1, 0, u + 1);
        WB_H(1, 0, lb0_0, lb0_1, lb0_2, lb0_3);
        MM(0);
        // ph2: | stage A(u+1).h1, load B(u+2).h0
        RD_BF(0, 0, 1);
        GLLA_H(1, 1, u + 1);
        LB_H(lb0_0, lb0_1, lb0_2, lb0_3, 0, u + 2);
        MM(1);
        // ph3: | write B(u+1).h1
        RD_AF(0, 1); RD_BF(0, 1, 0);
        WB_H(1, 1, lb1_0, lb1_1, lb1_2, lb1_3);
        MM(0);
        // ph4: | load B(u+2).h1; A(u+1) landed check
        RD_BF(0, 1, 1);
        LB_H(lb1_0, lb1_1, lb1_2, lb1_3, 1, u + 2);
        asm volatile("s_waitcnt vmcnt(8)" ::: "memory");
        MM(1);
        // ph5
        RD_AF(1, 0); RD_BF(1, 0, 0);
        GLLA_H(0, 0, u + 2);
        WB_H(0, 0, lb0_0, lb0_1, lb0_2, lb0_3);
        MM(0);
        // ph6
        RD_BF(1, 0, 1);
        GLLA_H(0, 1, u + 2);
        LB_H(lb0_0, lb0_1, lb0_2, lb0_3, 0, u + 3);
        MM(1);
        // ph7
        RD_AF(1, 1); RD_BF(1, 1, 0);
        WB_H(0, 1, lb1_0, lb1_1, lb1_2, lb1_3);
        MM(0);
        // ph8
        RD_BF(1, 1, 1);
        LB_H(lb1_0, lb1_1, lb1_2, lb1_3, 1, u + 3);
        asm volatile("s_waitcnt vmcnt(8)" ::: "memory");
        MM(1);
    }
#undef GLLA_H
#undef LB_H
#undef WB_H
#undef RD_AF
#undef RD_BF
#undef MM

    float* pc = part + ((size_t)bz << 20);
    int lh4 = lh * 4;
    #pragma unroll
    for (int mf = 0; mf < 8; mf++)
        #pragma unroll
        for (int nf = 0; nf < 4; nf++)
            #pragma unroll
            for (int r = 0; r < 4; r++)
                pc[(size_t)(tm + wr128 + mf * 16 + lh4 + r) * 1024 + (tn + wc64 + nf * 16 + lr)] = acc[mf][nf][r];
}

// ---------------- reduce split-K(14) + bias + BN + ReLU -> bf16 (x1) ----------------
__global__ void k_reduce1(const float* __restrict__ part, const float* __restrict__ bias,
                          const float* __restrict__ gam, const float* __restrict__ bet,
                          const float* __restrict__ mu, const float* __restrict__ var,
                          bf16* __restrict__ x1b) {
    int idx = blockIdx.x * 256 + threadIdx.x;
    int n = idx >> 8;
    int o = (idx & 255) << 2;
    f32x4 v = {};
    #pragma unroll
    for (int s = 0; s < 14; s++) v += *(const f32x4*)(part + ((size_t)s << 20) + (size_t)n * 1024 + o);
    f32x4 b4 = *(const f32x4*)(bias + o);
    f32x4 g4 = *(const f32x4*)(gam + o);
    f32x4 e4 = *(const f32x4*)(bet + o);
    f32x4 m4 = *(const f32x4*)(mu + o);
    f32x4 v4 = *(const f32x4*)(var + o);
    bf16x4 ov;
    #pragma unroll
    for (int e = 0; e < 4; e++) {
        float sc = g4[e] / sqrtf(v4[e] + 0.001f);
        float y = (v[e] + b4[e] - m4[e]) * sc + e4[e];
        y = fmaxf(y, 0.0f);
        if (n >= NROIS) y = 0.0f;
        ov[e] = (bf16)y;
    }
    *(bf16x4*)(x1b + (size_t)n * 1024 + o) = ov;
}

// ---------------- reduce split-K(4) + bias + BN + ReLU -> f32 (x2) ----------------
__global__ void k_reduce2(const float* __restrict__ part, const float* __restrict__ bias,
                          const float* __restrict__ gam, const float* __restrict__ bet,
                          const float* __restrict__ mu, const float* __restrict__ var,
                          float* __restrict__ x2) {
    int idx = blockIdx.x * 256 + threadIdx.x;
    int n = idx >> 8;
    int o = (idx & 255) << 2;
    f32x4 v = {};
    #pragma unroll
    for (int s = 0; s < 4; s++) v += *(const f32x4*)(part + ((size_t)s << 20) + (size_t)n * 1024 + o);
    f32x4 b4 = *(const f32x4*)(bias + o);
    f32x4 g4 = *(const f32x4*)(gam + o);
    f32x4 e4 = *(const f32x4*)(bet + o);
    f32x4 m4 = *(const f32x4*)(mu + o);
    f32x4 v4 = *(const f32x4*)(var + o);
    f32x4 ov;
    #pragma unroll
    for (int e = 0; e < 4; e++) {
        float sc = g4[e] / sqrtf(v4[e] + 0.001f);
        float y = (v[e] + b4[e] - m4[e]) * sc + e4[e];
        ov[e] = fmaxf(y, 0.0f);
    }
    *(f32x4*)(x2 + (size_t)n * 1024 + o) = ov;
}

// ---------------- heads ----------------
__device__ __forceinline__ float wred(float v) {
    #pragma unroll
    for (int off = 32; off; off >>= 1) v += __shfl_xor(v, off);
    return v;
}

__global__ void k_heads(const float* __restrict__ x2,
                        const float* __restrict__ wc, const float* __restrict__ bc,
                        const float* __restrict__ wb, const float* __restrict__ bb,
                        const float* __restrict__ wp, const float* __restrict__ bp,
                        float* __restrict__ out) {
    int w = threadIdx.x >> 6, l = threadIdx.x & 63;
    int n = blockIdx.x * 4 + w;
    float ac0 = 0.f, ac1 = 0.f, ab[8] = {}, ap[6] = {};
    const float* xr = x2 + (size_t)n * 1024;
    for (int kk = 0; kk < 16; kk++) {
        int k = kk * 64 + l;
        float xv = xr[k];
        ac0 += xv * wc[k];
        ac1 += xv * wc[1024 + k];
        #pragma unroll
        for (int o = 0; o < 8; o++) ab[o] += xv * wb[o * 1024 + k];
        #pragma unroll
        for (int o = 0; o < 6; o++) ap[o] += xv * wp[o * 1024 + k];
    }
    ac0 = wred(ac0); ac1 = wred(ac1);
    #pragma unroll
    for (int o = 0; o < 8; o++) ab[o] = wred(ab[o]);
    #pragma unroll
    for (int o = 0; o < 6; o++) ap[o] = wred(ap[o]);
    if (l == 0) {
        float l0 = ac0 + bc[0], l1 = ac1 + bc[1];
        out[n * 2] = l0; out[n * 2 + 1] = l1;
        float m = fmaxf(l0, l1);
        float e0 = expf(l0 - m), e1 = expf(l1 - m);
        float inv = 1.0f / (e0 + e1);
        out[2000 + n * 2] = e0 * inv; out[2000 + n * 2 + 1] = e1 * inv;
        #pragma unroll
        for (int o = 0; o < 8; o++) out[4000 + n * 8 + o] = ab[o] + bb[o];
        #pragma unroll
        for (int o = 0; o < 6; o++) out[12000 + n * 6 + o] = ap[o] + bp[o];
    }
}

extern "C" void kernel_launch(void* const* d_in, const int* in_sizes, int n_in,
                              void* d_out, int out_size, void* d_ws, size_t ws_size,
                              hipStream_t stream) {
    const float* p2      = (const float*)d_in[0];
    const float* p3      = (const float*)d_in[1];
    const float* p4      = (const float*)d_in[2];
    const float* p5      = (const float*)d_in[3];
    const float* rois    = (const float*)d_in[4];
    const float* ranges  = (const float*)d_in[5];
    const float* conv1_w = (const float*)d_in[6];
    const float* conv1_b = (const float*)d_in[7];
    const float* bn1_g   = (const float*)d_in[8];
    const float* bn1_b   = (const float*)d_in[9];
    const float* bn1_m   = (const float*)d_in[10];
    const float* bn1_v   = (const float*)d_in[11];
    const float* conv2_w = (const float*)d_in[12];
    const float* conv2_b = (const float*)d_in[13];
    const float* bn2_g   = (const float*)d_in[14];
    const float* bn2_b   = (const float*)d_in[15];
    const float* bn2_m   = (const float*)d_in[16];
    const float* bn2_v   = (const float*)d_in[17];
    const float* wc      = (const float*)d_in[18];
    const float* bc      = (const float*)d_in[19];
    const float* wb      = (const float*)d_in[20];
    const float* bb      = (const float*)d_in[21];
    const float* wp      = (const float*)d_in[22];
    const float* bp      = (const float*)d_in[23];

    char* ws = (char*)d_ws;
    bf16*  A    = (bf16*)(ws + OFF_A);
    float* part = (float*)(ws + OFF_PART);
    float* tab  = (float*)(ws + OFF_TAB);
    float* T    = (float*)(ws + OFF_T);
    bf16*  x1b  = (bf16*)(ws + OFF_X1B);
    float* x2   = (float*)(ws + OFF_X2);
    float* out  = (float*)d_out;

    k_prep<<<2532, 256, 0, stream>>>(p2, p3, p4, p5, ranges, T, rois, tab);
    k_crop2<<<1024, 256, 0, stream>>>(T, tab, out + 18000, A);
    // GEMM1: M=1024 x N=1024 x K=16128(pad), 256x256, z=14, NT=18
    k_gemm8p<1><<<224, 512, 0, stream>>>(A, conv1_w, part, KPAD, KDIM, 18);
    k_reduce1<<<1024, 256, 0, stream>>>(part, conv1_b, bn1_g, bn1_b, bn1_m, bn1_v, x1b);
    // GEMM2: K=1024, z=4, NT=4
    k_gemm8p<0><<<dim3(4, 4, 4), 512, 0, stream>>>(x1b, conv2_w, part, 1024, 1024, 4);
    k_reduce2<<<1024, 256, 0, stream>>>(part, conv2_b, bn2_g, bn2_b, bn2_m, bn2_v, x2);
    k_heads<<<250, 256, 0, stream>>>(x2, wc, bc, wb, bb, wp, bp, out);
}

// Round 7
// 165.887 us; speedup vs baseline: 1.0380x; 1.0380x over previous
//
#include <hip/hip_runtime.h>
#include <hip/hip_bf16.h>
#include <stdint.h>

typedef __bf16 bf16;
typedef __bf16 bf16x8 __attribute__((ext_vector_type(8)));
typedef __bf16 bf16x4 __attribute__((ext_vector_type(4)));
typedef __bf16 bf16x2 __attribute__((ext_vector_type(2)));
typedef float f32x4 __attribute__((ext_vector_type(4)));
typedef float f32x2 __attribute__((ext_vector_type(2)));
typedef int i32x4 __attribute__((ext_vector_type(4)));

#define GAS __attribute__((address_space(1)))
#define LAS __attribute__((address_space(3)))

#define NROIS 1000
#define DEPTH 256
#define CIN 320
#define KDIM 15680      // 320*49 = 245 K-tiles of 64
#define KPAD 16128      // 252 tiles = 14 z-slices x 18
#define TABS 120

// NHWC offsets (floats, within T region)
#define T_P2 0
#define T_P3 6553600
#define T_P4 8192000
#define T_P5 8601600
#define T_RNG 8704000

// ws layout (aliased; stream-ordered). Proven budget >= 100,401,152 B.
#define OFF_A    0ULL
#define OFF_PART 33030144ULL
#define OFF_TAB  33030144ULL
#define OFF_T    33554432ULL
#define OFF_X1B  0ULL
#define OFF_X2   2621440ULL

// ---------------- prep: CHW->HWC transpose + per-ROI tables (merged) ----------------
__global__ __launch_bounds__(256) void k_prep(const float* __restrict__ p2, const float* __restrict__ p3,
                                              const float* __restrict__ p4, const float* __restrict__ p5,
                                              const float* __restrict__ rng, float* __restrict__ T,
                                              const float* __restrict__ rois, float* __restrict__ tab) {
    __shared__ float tile[64][65];
    int bid = blockIdx.x, t = threadIdx.x;
    if (bid >= 2528) {   // roi table blocks
        int n = (bid - 2528) * 256 + t;
        if (n >= NROIS) return;
        float y1 = rois[n*4+0], x1 = rois[n*4+1], y2 = rois[n*4+2], x2 = rois[n*4+3];
        float h = __fsub_rn(y2, y1), w = __fsub_rn(x2, x1);
        float rl = 4.0f + logf(sqrtf(h * w) / (224.0f / 640.0f)) / logf(2.0f);
        int lvl = (int)rintf(rl);
        lvl = min(5, max(2, lvl));
        float* tt = tab + (size_t)n * TABS;
        tt[112] = (float)lvl;
        int Hs0 = 160 >> (lvl - 2);
        for (int g = 0; g < 2; g++) {
            int H = g ? 160 : Hs0;
            float* tg = tt + g * 56;
            float fH = (float)(H - 1);
            float a = __fmul_rn(y1, fH);
            float s = __fdiv_rn(__fmul_rn(h, fH), 6.0f);
            for (int i = 0; i < 7; i++) {
                float iny = __fadd_rn(a, __fmul_rn((float)i, s));
                float tp = floorf(iny), bt = ceilf(iny);
                tg[i]      = (float)min(H-1, max(0, (int)tp));
                tg[7 + i]  = (float)min(H-1, max(0, (int)bt));
                tg[14 + i] = iny - tp;
                tg[21 + i] = (iny >= 0.0f && iny <= fH) ? 1.0f : 0.0f;
            }
            a = __fmul_rn(x1, fH);
            s = __fdiv_rn(__fmul_rn(w, fH), 6.0f);
            for (int j = 0; j < 7; j++) {
                float inx = __fadd_rn(a, __fmul_rn((float)j, s));
                float lf = floorf(inx), rt = ceilf(inx);
                tg[28 + j] = (float)min(H-1, max(0, (int)lf));
                tg[35 + j] = (float)min(H-1, max(0, (int)rt));
                tg[42 + j] = inx - lf;
                tg[49 + j] = (inx >= 0.0f && inx <= fH) ? 1.0f : 0.0f;
            }
        }
        return;
    }
    const float* src; float* dst; int C, X, loc;
    if (bid < 1600)      { src = p2;  dst = T + T_P2;  C = 256; X = 25600; loc = bid; }
    else if (bid < 2000) { src = p3;  dst = T + T_P3;  C = 256; X = 6400;  loc = bid - 1600; }
    else if (bid < 2100) { src = p4;  dst = T + T_P4;  C = 256; X = 1600;  loc = bid - 2000; }
    else if (bid < 2128) { src = p5;  dst = T + T_P5;  C = 256; X = 400;   loc = bid - 2100; }
    else                 { src = rng; dst = T + T_RNG; C = 64;  X = 25600; loc = bid - 2128; }
    int xtiles = (X + 63) >> 6;
    int xt = loc % xtiles, ct = loc / xtiles;
    int x0 = xt << 6, c0 = ct << 6;
    #pragma unroll
    for (int r = 0; r < 16; r++) {
        int lin = r * 256 + t;
        int lc = lin >> 6, lx = lin & 63;
        int x = x0 + lx;
        tile[lc][lx] = (x < X) ? src[(size_t)(c0 + lc) * X + x] : 0.0f;
    }
    __syncthreads();
    #pragma unroll
    for (int r = 0; r < 16; r++) {
        int lin = r * 256 + t;
        int lxx = lin >> 6, lcc = lin & 63;
        int x = x0 + lxx;
        if (x < X) dst[(size_t)x * C + c0 + lcc] = tile[lcc][lxx];
    }
}

// ---------------- crop_and_resize from NHWC ----------------
#define RES_S 329
__global__ __launch_bounds__(256) void k_crop2(const float* __restrict__ T, const float* __restrict__ tab,
                                               float* __restrict__ out_rf, bf16* __restrict__ A) {
    int n = blockIdx.x, t = threadIdx.x;
    if (n >= NROIS) {                 // zero-pad A rows 1000..1023
        i32x4* row = (i32x4*)(A + (size_t)n * KPAD);
        for (int i = t; i < KPAD * 2 / 16; i += 256) row[i] = i32x4{0,0,0,0};
        return;
    }
    __shared__ float res[49 * RES_S];
    __shared__ float tl_[TABS];
    if (t < TABS) tl_[t] = tab[(size_t)n * TABS + t];
    __syncthreads();
    int lvl = (int)tl_[112];
    int H = 160 >> (lvl - 2);
    int toff = (lvl == 2) ? T_P2 : (lvl == 3) ? T_P3 : (lvl == 4) ? T_P4 : T_P5;
    const float* F = T + toff;
    {
        int q = t & 63, pl = t >> 6, c4 = q * 4;
        for (int g = 0; g < 13; g++) {
            int pos = g * 4 + pl;
            if (pos < 49) {
                int i = pos / 7, j = pos % 7;
                int ti = (int)tl_[i],      bi = (int)tl_[7 + i];
                int li = (int)tl_[28 + j], ri = (int)tl_[35 + j];
                float ly = tl_[14 + i], lx = tl_[42 + j];
                float valid = tl_[21 + i] * tl_[49 + j];
                f32x4 vtl = *(const f32x4*)(F + (size_t)(ti * H + li) * 256 + c4);
                f32x4 vtr = *(const f32x4*)(F + (size_t)(ti * H + ri) * 256 + c4);
                f32x4 vbl = *(const f32x4*)(F + (size_t)(bi * H + li) * 256 + c4);
                f32x4 vbr = *(const f32x4*)(F + (size_t)(bi * H + ri) * 256 + c4);
                f32x4 top = vtl + (vtr - vtl) * lx;
                f32x4 bot = vbl + (vbr - vbl) * lx;
                f32x4 v = top + (bot - top) * ly;
                if (valid == 0.0f) v = f32x4{0.f,0.f,0.f,0.f};
                *(f32x4*)(&res[pos * RES_S + c4]) = v;
            }
        }
    }
    {
        int q = t & 15, pl = t >> 4, c4 = q * 4;
        const float* R = T + T_RNG;
        for (int g = 0; g < 4; g++) {
            int pos = g * 16 + pl;
            if (pos < 49) {
                int i = pos / 7, j = pos % 7;
                int ti = (int)tl_[56 + i], bi = (int)tl_[63 + i];
                int li = (int)tl_[84 + j], ri = (int)tl_[91 + j];
                float ly = tl_[70 + i], lx = tl_[98 + j];
                float valid = tl_[77 + i] * tl_[105 + j];
                f32x4 vtl = *(const f32x4*)(R + (size_t)(ti * 160 + li) * 64 + c4);
                f32x4 vtr = *(const f32x4*)(R + (size_t)(ti * 160 + ri) * 64 + c4);
                f32x4 vbl = *(const f32x4*)(R + (size_t)(bi * 160 + li) * 64 + c4);
                f32x4 vbr = *(const f32x4*)(R + (size_t)(bi * 160 + ri) * 64 + c4);
                f32x4 top = vtl + (vtr - vtl) * lx;
                f32x4 bot = vbl + (vbr - vbl) * lx;
                f32x4 v = top + (bot - top) * ly;
                if (valid == 0.0f) v = f32x4{0.f,0.f,0.f,0.f};
                *(f32x4*)(&res[pos * RES_S + 256 + c4]) = v;
            }
        }
    }
    __syncthreads();
    size_t ob = (size_t)n * KDIM;
    size_t ab = (size_t)n * KPAD;
    for (int k = 0; k < 31; k++) {
        int i2 = (k * 256 + t) * 2;
        if (i2 < KDIM) {
            float e0 = res[(i2 % 49) * RES_S + i2 / 49];
            int i3 = i2 + 1;
            float e1 = res[(i3 % 49) * RES_S + i3 / 49];
            *(f32x2*)(out_rf + ob + i2) = f32x2{e0, e1};
            bf16x2 b2; b2[0] = (bf16)e0; b2[1] = (bf16)e1;
            *(bf16x2*)(A + ab + i2) = b2;
        }
    }
    if (t < 56) ((i32x4*)(A + ab + KDIM))[t] = i32x4{0,0,0,0};
}

// ---------------- 256x256 counted-vmcnt GEMM, one barrier-pair per K-tile ----------------
// [256][64] XOR-swizzled LDS (zero-conflict, R4/R6-verified). A bf16 via global_load_lds
// (pre-swizzled source); B f32 reg-loaded 2 tiles early -> cvt -> swizzled ds_write.
// Per-region: waitcnt(12)+lgkm(0); barrier; {24 ds_read + 64 MFMA overlap}; WB(t+1);
// LB(t+2); barrier; GLLA(t+2).  VMEM in flight per wave is exactly 12 at entry.
template<int REMAP>
__global__ __launch_bounds__(512, 2)
void k_gemmct(const bf16* __restrict__ A, const float* __restrict__ Bf,
              float* __restrict__ part, const int KA, const int KB, const int NT) {
    __shared__ bf16 sA[2][16384];   // [buf][256 rows][64 cols], slot^(row&7)
    __shared__ bf16 sB[2][16384];
    int tid = threadIdx.x;
    int l = tid & 63, w = tid >> 6;
    int bx, by, bz;
    if (REMAP) {
        int id = blockIdx.x;
        int z, j;
        if (id < 128) { z = id & 7; j = id >> 3; }
        else { int r = id - 128; z = 8 + (r >> 4); j = r & 15; }
        bx = j & 3; by = j >> 2; bz = z;
    } else { bx = blockIdx.x; by = blockIdx.y; bz = blockIdx.z; }
    int tm = bx * 256, tn = by * 256;
    int t0 = bz * NT;
    const int maxTA = KA / 64 - 1;
    const int maxBC = KB - 64;

    int wr128 = (w >> 2) * 128;
    int wc64  = (w & 3) * 64;
    int lr = l & 15, lh = l >> 4;
    int sxor = lr & 7;

    int idx0 = tid;
    int arl = idx0 >> 3, aslot = idx0 & 7;
    const bf16* Asrc = A + (size_t)(tm + arl) * KA + ((aslot ^ (arl & 7)) << 3);
    int brw = idx0 >> 2, bc4 = idx0 & 3;
    const float* Bsrc = Bf + (size_t)(tn + brw) * KB + bc4 * 16;
    int bsw0 = ((bc4 * 2) ^ (brw & 7)) << 3;
    int bsw1 = ((bc4 * 2 + 1) ^ (brw & 7)) << 3;
    int brow64 = brw * 64;

    f32x4 acc[8][4] = {};
    bf16x8 af[8], b0, b1;
    f32x4 lb0_0, lb0_1, lb0_2, lb0_3;
    f32x4 lb1_0, lb1_1, lb1_2, lb1_3;

#define GLLA_H(bufc, h_, t_) do { int tt_ = min((t_), maxTA); size_t kc_ = (size_t)tt_ * 64; \
    __builtin_amdgcn_global_load_lds((const GAS void*)(Asrc + (size_t)((h_) * 128) * KA + kc_), \
        (LAS void*)(&sA[bufc][(h_) * 8192 + idx0 * 8]), 16, 0, 0); \
    __builtin_amdgcn_global_load_lds((const GAS void*)(Asrc + (size_t)((h_) * 128 + 64) * KA + kc_), \
        (LAS void*)(&sA[bufc][(h_) * 8192 + 4096 + idx0 * 8]), 16, 0, 0); \
} while (0)

#define LB_H(R0, R1, R2, R3, h_, t_) do { \
    const float* p_ = Bsrc + (size_t)((h_) * 128) * KB + min((t_) * 64, maxBC); \
    R0 = *(const f32x4*)(p_);     R1 = *(const f32x4*)(p_ + 4); \
    R2 = *(const f32x4*)(p_ + 8); R3 = *(const f32x4*)(p_ + 12); \
} while (0)

#define WB_H(bufc, h_, R0, R1, R2, R3) do { bf16x8 w0_, w1_; \
    _Pragma("unroll") for (int e_ = 0; e_ < 4; e_++) { \
        w0_[e_] = (bf16)R0[e_]; w0_[4 + e_] = (bf16)R1[e_]; \
        w1_[e_] = (bf16)R2[e_]; w1_[4 + e_] = (bf16)R3[e_]; } \
    *(bf16x8*)(&sB[bufc][(h_) * 8192 + brow64 + bsw0]) = w0_; \
    *(bf16x8*)(&sB[bufc][(h_) * 8192 + brow64 + bsw1]) = w1_; \
} while (0)

#define RD_AF(bufc, ks_) do { _Pragma("unroll") for (int mf_ = 0; mf_ < 8; mf_++) \
    af[mf_] = *(const bf16x8*)(&sA[bufc][(wr128 + mf_ * 16 + lr) * 64 + ((((ks_) * 4 + lh) ^ sxor) << 3)]); \
} while (0)

#define RD_BF(bufc, ks_, nh_) do { \
    b0 = *(const bf16x8*)(&sB[bufc][(wc64 + (nh_) * 32 + lr) * 64 + ((((ks_) * 4 + lh) ^ sxor) << 3)]); \
    b1 = *(const bf16x8*)(&sB[bufc][(wc64 + (nh_) * 32 + 16 + lr) * 64 + ((((ks_) * 4 + lh) ^ sxor) << 3)]); \
} while (0)

#define MFMA16(nh_) do { \
    __builtin_amdgcn_s_setprio(1); \
    _Pragma("unroll") for (int mf_ = 0; mf_ < 8; mf_++) { \
        acc[mf_][(nh_) * 2]     = __builtin_amdgcn_mfma_f32_16x16x32_bf16(af[mf_], b0, acc[mf_][(nh_) * 2], 0, 0, 0); \
        acc[mf_][(nh_) * 2 + 1] = __builtin_amdgcn_mfma_f32_16x16x32_bf16(af[mf_], b1, acc[mf_][(nh_) * 2 + 1], 0, 0, 0); } \
    __builtin_amdgcn_s_setprio(0); \
} while (0)

    // ---- prologue: tile t0 staged into buf0; tile t0+1 VMEM in flight ----
    LB_H(lb0_0, lb0_1, lb0_2, lb0_3, 0, t0);      // 8 (oldest)
    LB_H(lb1_0, lb1_1, lb1_2, lb1_3, 1, t0);
    GLLA_H(0, 0, t0); GLLA_H(0, 1, t0);           // 4
    WB_H(0, 0, lb0_0, lb0_1, lb0_2, lb0_3);       // reg-dep waits B(t0), keeps A(t0) in flight
    WB_H(0, 1, lb1_0, lb1_1, lb1_2, lb1_3);
    LB_H(lb0_0, lb0_1, lb0_2, lb0_3, 0, t0 + 1);  // 8
    LB_H(lb1_0, lb1_1, lb1_2, lb1_3, 1, t0 + 1);
    GLLA_H(1, 0, t0 + 1); GLLA_H(1, 1, t0 + 1);   // 4  -> outstanding = A(t0)4 + 12

    int p = 0;
    for (int t = t0; t < t0 + NT; t++) {
        // region entry: drain tile-t data (A gloads + my B ds_writes); keep t+1's 12 in flight
        asm volatile("s_waitcnt vmcnt(12) lgkmcnt(0)" ::: "memory");
        __builtin_amdgcn_s_barrier();
        asm volatile("" ::: "memory");
        // compute tile t from buf p; compiler interleaves ds_read with MFMA
        RD_AF(p, 0); RD_BF(p, 0, 0);
        MFMA16(0);
        RD_BF(p, 0, 1);
        MFMA16(1);
        RD_AF(p, 1); RD_BF(p, 1, 0);
        MFMA16(0);
        RD_BF(p, 1, 1);
        MFMA16(1);
        // write B(t+1) into buf p^1 (disjoint from readers), then load B(t+2) into regs
        WB_H(p ^ 1, 0, lb0_0, lb0_1, lb0_2, lb0_3);
        WB_H(p ^ 1, 1, lb1_0, lb1_1, lb1_2, lb1_3);
        LB_H(lb0_0, lb0_1, lb0_2, lb0_3, 0, t + 2);
        LB_H(lb1_0, lb1_1, lb1_2, lb1_3, 1, t + 2);
        // all reads of buf p done -> safe to overwrite with A(t+2)
        asm volatile("" ::: "memory");
        __builtin_amdgcn_s_barrier();
        asm volatile("" ::: "memory");
        GLLA_H(p, 0, t + 2); GLLA_H(p, 1, t + 2);
        p ^= 1;
    }
#undef GLLA_H
#undef LB_H
#undef WB_H
#undef RD_AF
#undef RD_BF
#undef MFMA16

    float* pc = part + ((size_t)bz << 20);
    int lh4 = lh * 4;
    #pragma unroll
    for (int mf = 0; mf < 8; mf++)
        #pragma unroll
        for (int nf = 0; nf < 4; nf++)
            #pragma unroll
            for (int r = 0; r < 4; r++)
                pc[(size_t)(tm + wr128 + mf * 16 + lh4 + r) * 1024 + (tn + wc64 + nf * 16 + lr)] = acc[mf][nf][r];
}

// ---------------- reduce split-K(14) + bias + BN + ReLU -> bf16 (x1) ----------------
__global__ void k_reduce1(const float* __restrict__ part, const float* __restrict__ bias,
                          const float* __restrict__ gam, const float* __restrict__ bet,
                          const float* __restrict__ mu, const float* __restrict__ var,
                          bf16* __restrict__ x1b) {
    int idx = blockIdx.x * 256 + threadIdx.x;
    int n = idx >> 8;
    int o = (idx & 255) << 2;
    f32x4 v = {};
    #pragma unroll
    for (int s = 0; s < 14; s++) v += *(const f32x4*)(part + ((size_t)s << 20) + (size_t)n * 1024 + o);
    f32x4 b4 = *(const f32x4*)(bias + o);
    f32x4 g4 = *(const f32x4*)(gam + o);
    f32x4 e4 = *(const f32x4*)(bet + o);
    f32x4 m4 = *(const f32x4*)(mu + o);
    f32x4 v4 = *(const f32x4*)(var + o);
    bf16x4 ov;
    #pragma unroll
    for (int e = 0; e < 4; e++) {
        float sc = g4[e] / sqrtf(v4[e] + 0.001f);
        float y = (v[e] + b4[e] - m4[e]) * sc + e4[e];
        y = fmaxf(y, 0.0f);
        if (n >= NROIS) y = 0.0f;
        ov[e] = (bf16)y;
    }
    *(bf16x4*)(x1b + (size_t)n * 1024 + o) = ov;
}

// ---------------- reduce split-K(8) + bias + BN + ReLU -> f32 (x2) ----------------
__global__ void k_reduce2(const float* __restrict__ part, const float* __restrict__ bias,
                          const float* __restrict__ gam, const float* __restrict__ bet,
                          const float* __restrict__ mu, const float* __restrict__ var,
                          float* __restrict__ x2) {
    int idx = blockIdx.x * 256 + threadIdx.x;
    int n = idx >> 8;
    int o = (idx & 255) << 2;
    f32x4 v = {};
    #pragma unroll
    for (int s = 0; s < 8; s++) v += *(const f32x4*)(part + ((size_t)s << 20) + (size_t)n * 1024 + o);
    f32x4 b4 = *(const f32x4*)(bias + o);
    f32x4 g4 = *(const f32x4*)(gam + o);
    f32x4 e4 = *(const f32x4*)(bet + o);
    f32x4 m4 = *(const f32x4*)(mu + o);
    f32x4 v4 = *(const f32x4*)(var + o);
    f32x4 ov;
    #pragma unroll
    for (int e = 0; e < 4; e++) {
        float sc = g4[e] / sqrtf(v4[e] + 0.001f);
        float y = (v[e] + b4[e] - m4[e]) * sc + e4[e];
        ov[e] = fmaxf(y, 0.0f);
    }
    *(f32x4*)(x2 + (size_t)n * 1024 + o) = ov;
}

// ---------------- heads ----------------
__device__ __forceinline__ float wred(float v) {
    #pragma unroll
    for (int off = 32; off; off >>= 1) v += __shfl_xor(v, off);
    return v;
}

__global__ void k_heads(const float* __restrict__ x2,
                        const float* __restrict__ wc, const float* __restrict__ bc,
                        const float* __restrict__ wb, const float* __restrict__ bb,
                        const float* __restrict__ wp, const float* __restrict__ bp,
                        float* __restrict__ out) {
    int w = threadIdx.x >> 6, l = threadIdx.x & 63;
    int n = blockIdx.x * 4 + w;
    float ac0 = 0.f, ac1 = 0.f, ab[8] = {}, ap[6] = {};
    const float* xr = x2 + (size_t)n * 1024;
    for (int kk = 0; kk < 16; kk++) {
        int k = kk * 64 + l;
        float xv = xr[k];
        ac0 += xv * wc[k];
        ac1 += xv * wc[1024 + k];
        #pragma unroll
        for (int o = 0; o < 8; o++) ab[o] += xv * wb[o * 1024 + k];
        #pragma unroll
        for (int o = 0; o < 6; o++) ap[o] += xv * wp[o * 1024 + k];
    }
    ac0 = wred(ac0); ac1 = wred(ac1);
    #pragma unroll
    for (int o = 0; o < 8; o++) ab[o] = wred(ab[o]);
    #pragma unroll
    for (int o = 0; o < 6; o++) ap[o] = wred(ap[o]);
    if (l == 0) {
        float l0 = ac0 + bc[0], l1 = ac1 + bc[1];
        out[n * 2] = l0; out[n * 2 + 1] = l1;
        float m = fmaxf(l0, l1);
        float e0 = expf(l0 - m), e1 = expf(l1 - m);
        float inv = 1.0f / (e0 + e1);
        out[2000 + n * 2] = e0 * inv; out[2000 + n * 2 + 1] = e1 * inv;
        #pragma unroll
        for (int o = 0; o < 8; o++) out[4000 + n * 8 + o] = ab[o] + bb[o];
        #pragma unroll
        for (int o = 0; o < 6; o++) out[12000 + n * 6 + o] = ap[o] + bp[o];
    }
}

extern "C" void kernel_launch(void* const* d_in, const int* in_sizes, int n_in,
                              void* d_out, int out_size, void* d_ws, size_t ws_size,
                              hipStream_t stream) {
    const float* p2      = (const float*)d_in[0];
    const float* p3      = (const float*)d_in[1];
    const float* p4      = (const float*)d_in[2];
    const float* p5      = (const float*)d_in[3];
    const float* rois    = (const float*)d_in[4];
    const float* ranges  = (const float*)d_in[5];
    const float* conv1_w = (const float*)d_in[6];
    const float* conv1_b = (const float*)d_in[7];
    const float* bn1_g   = (const float*)d_in[8];
    const float* bn1_b   = (const float*)d_in[9];
    const float* bn1_m   = (const float*)d_in[10];
    const float* bn1_v   = (const float*)d_in[11];
    const float* conv2_w = (const float*)d_in[12];
    const float* conv2_b = (const float*)d_in[13];
    const float* bn2_g   = (const float*)d_in[14];
    const float* bn2_b   = (const float*)d_in[15];
    const float* bn2_m   = (const float*)d_in[16];
    const float* bn2_v   = (const float*)d_in[17];
    const float* wc      = (const float*)d_in[18];
    const float* bc      = (const float*)d_in[19];
    const float* wb      = (const float*)d_in[20];
    const float* bb      = (const float*)d_in[21];
    const float* wp      = (const float*)d_in[22];
    const float* bp      = (const float*)d_in[23];

    char* ws = (char*)d_ws;
    bf16*  A    = (bf16*)(ws + OFF_A);
    float* part = (float*)(ws + OFF_PART);
    float* tab  = (float*)(ws + OFF_TAB);
    float* T    = (float*)(ws + OFF_T);
    bf16*  x1b  = (bf16*)(ws + OFF_X1B);
    float* x2   = (float*)(ws + OFF_X2);
    float* out  = (float*)d_out;

    k_prep<<<2532, 256, 0, stream>>>(p2, p3, p4, p5, ranges, T, rois, tab);
    k_crop2<<<1024, 256, 0, stream>>>(T, tab, out + 18000, A);
    // GEMM1: M=1024 x N=1024 x K=16128(pad), 256x256, z=14, NT=18
    k_gemmct<1><<<224, 512, 0, stream>>>(A, conv1_w, part, KPAD, KDIM, 18);
    k_reduce1<<<1024, 256, 0, stream>>>(part, conv1_b, bn1_g, bn1_b, bn1_m, bn1_v, x1b);
    // GEMM2: K=1024, z=8, NT=2 (128 blocks)
    k_gemmct<0><<<dim3(4, 4, 8), 512, 0, stream>>>(x1b, conv2_w, part, 1024, 1024, 2);
    k_reduce2<<<1024, 256, 0, stream>>>(part, conv2_b, bn2_g, bn2_b, bn2_m, bn2_v, x2);
    k_heads<<<250, 256, 0, stream>>>(x2, wc, bc, wb, bb, wp, bp, out);
}